// Round 2
// baseline (83.552 us; speedup 1.0000x reference)
//
#include <hip/hip_runtime.h>

typedef float f2 __attribute__((ext_vector_type(2)));

namespace {
constexpr int kB = 4;
constexpr int kN = 4096;             // points per set per batch (N == M)
constexpr int kPts = kB * kN;        // per set = 16384
constexpr int kP = 2 * kPts;         // all per-point mins = 32768
constexpr int kBlk = 256;
constexpr int kPairs = 16;           // staged other-PAIRS per lane (32 pts)
constexpr int kOthersPerWave = 64 * 2 * kPairs;  // 2048
constexpr int kOSeg = kN / kOthersPerWave;       // 2 other-segments
constexpr int kOwnsPerWave = 16;
constexpr int kOwnsPerBlk = 4 * kOwnsPerWave;    // 64 (4 waves/block)
constexpr float kInf = 3.4e38f;
}

// ws layout: [keys: kP u32][pack: kP float4 worth of pair-interleaved floats]
// Pair-interleaved pack: for point pair g, float4 pack4[2g] = {x0,x1,y0,y1},
// pack4[2g+1] = {z0,z1,w0,w1}, w = ||p||^2. Pairs [0, kPts/2) = target set,
// [kPts/2, kP/2) = source set.

// Monotone float<->uint map: unsigned atomicMin orders all floats (partial
// e = ||y||^2 - 2 x.y can be negative).
__device__ __forceinline__ unsigned enc(float f) {
  unsigned u = __float_as_uint(f);
  return (u & 0x80000000u) ? ~u : (u | 0x80000000u);
}
__device__ __forceinline__ float dec(unsigned k) {
  return __uint_as_float((k & 0x80000000u) ? (k ^ 0x80000000u) : ~k);
}

// One thread per point PAIR: contiguous 24B read, two float4 stores, one
// uint2 key-init. Pairs never straddle the set boundary (kPts even).
__global__ __launch_bounds__(kBlk) void cham_prep_kernel(
    const float* __restrict__ src, const float* __restrict__ tgt,
    float4* __restrict__ pack4, unsigned* __restrict__ keys,
    float* __restrict__ out) {
  int g = blockIdx.x * kBlk + threadIdx.x;  // pair id, grid covers kP/2
  const float* p = (g < kPts / 2) ? (tgt + (size_t)g * 6)
                                  : (src + (size_t)(g - kPts / 2) * 6);
  const f2 a = *(const f2*)(p);      // {x0, y0}   (8B-aligned: 24g % 8 == 0)
  const f2 bv = *(const f2*)(p + 2); // {z0, x1}
  const f2 c = *(const f2*)(p + 4);  // {y1, z1}
  const float x0 = a.x, y0 = a.y, z0 = bv.x;
  const float x1 = bv.y, y1 = c.x, z1 = c.y;
  const float w0 = fmaf(x0, x0, fmaf(y0, y0, z0 * z0));
  const float w1 = fmaf(x1, x1, fmaf(y1, y1, z1 * z1));
  pack4[2 * g] = make_float4(x0, x1, y0, y1);
  pack4[2 * g + 1] = make_float4(z0, z1, w0, w1);
  ((uint2*)keys)[g] = make_uint2(0xFFFFFFFFu, 0xFFFFFFFFu);  // +max
  if (g == 0) out[0] = 0.0f;
}

// Inverted placement vs R1: each WAVE stages 2048 other points in VGPRs
// (32/lane, pair-interleaved f2, xyz pre-scaled by -2) ONCE, then streams
// 16 own points via wave-uniform s_load. Inner loop is pure VALU — zero
// memory ops, zero lgkmcnt waits: per other-pair, 3 v_pk_fma + 1 v_min3
// (W2 is a VGPR now, so it folds into the fma chain; no 2-SGPR-operand
// issue). Per own: 64 core + ~6 dup-setup + 12 shfl_xor-min reduce +
// 1 atomic from lane 0 => ~2.6 lane-instr/eval, ~4.7 us issue floor.
// Atomics: kOSeg per key = 131K total (4x fewer than R1).
// ~160 VGPR (128 staged) -> 3 waves/SIMD; fine: little latency to hide.
__global__ __launch_bounds__(kBlk, 3) void cham_min_kernel(
    const float4* __restrict__ pack4, unsigned* __restrict__ keys) {
  const int dir = blockIdx.z;  // 0: s->t (other = tgt = first half), 1: t->s
  const int b = blockIdx.y;
  const int oseg = blockIdx.x & (kOSeg - 1);
  const int ownBlk = blockIdx.x >> 1;  // kOSeg == 2
  const int wave = threadIdx.x >> 6;
  const int lane = threadIdx.x & 63;

  // ---- stage others: lane's pair r = gBase + r*64 + lane ----
  const size_t gBase = ((size_t)dir * kPts + (size_t)b * kN) / 2 +
                       (size_t)oseg * (kOthersPerWave / 2);
  f2 X2[kPairs], Y2[kPairs], Z2[kPairs], W2[kPairs];
#pragma unroll
  for (int r = 0; r < kPairs; ++r) {
    const size_t gp = gBase + (size_t)(r * 64 + lane);
    const float4 A = pack4[2 * gp];       // {x_a, x_b, y_a, y_b}
    const float4 Bv = pack4[2 * gp + 1];  // {z_a, z_b, w_a, w_b}
    X2[r] = f2{-2.0f * A.x, -2.0f * A.y};   // v_pk_mul with -2.0 inline
    Y2[r] = f2{-2.0f * A.z, -2.0f * A.w};
    Z2[r] = f2{-2.0f * Bv.x, -2.0f * Bv.y};
    W2[r] = f2{Bv.z, Bv.w};
  }

  // ---- own points: 16 consecutive, uniform (SGPR-resident) ----
  const int own0 = ownBlk * kOwnsPerBlk + wave * kOwnsPerWave;
  const size_t ownPt = (size_t)(1 - dir) * kPts + (size_t)b * kN + own0;
  const float4* __restrict__ ownp = pack4 + ownPt;  // own0 even: pair-aligned
  unsigned* __restrict__ kb = keys + ((size_t)dir * kB + b) * kN + own0;

  for (int ob = 0; ob < kOwnsPerWave / 4; ++ob) {  // 4 owns per batch:
    float red[4], wo[4];                           // reduce tails pipeline
#pragma unroll
    for (int u = 0; u < 4; ++u) {
      const int k = ob * 4 + u;
      const float4 A = ownp[2 * (k >> 1)];      // s_load, CSE'd per pair
      const float4 Bo = ownp[2 * (k >> 1) + 1];
      const float x = (k & 1) ? A.y : A.x;
      const float y = (k & 1) ? A.w : A.z;
      const float z = (k & 1) ? Bo.y : Bo.x;
      wo[u] = (k & 1) ? Bo.w : Bo.z;
      const f2 dx = f2{x, x};  // dup'd once per own, hoisted over 64 fmas
      const f2 dy = f2{y, y};
      const f2 dz = f2{z, z};
      float ea = kInf, eb = kInf;
#pragma unroll
      for (int r = 0; r < kPairs; ++r) {
        const f2 e = __builtin_elementwise_fma(
            X2[r], dx,
            __builtin_elementwise_fma(Y2[r], dy,
                                      __builtin_elementwise_fma(Z2[r], dz,
                                                                W2[r])));
        if (r & 1) eb = fminf(fminf(e.x, e.y), eb);  // v_min3, 2 chains
        else       ea = fminf(fminf(e.x, e.y), ea);
      }
      red[u] = fminf(ea, eb);
    }
    // 4 independent cross-lane min chains — latencies overlap
#pragma unroll
    for (int u = 0; u < 4; ++u)
#pragma unroll
      for (int m = 1; m < 64; m <<= 1)
        red[u] = fminf(red[u], __shfl_xor(red[u], m, 64));
    if (lane == 0) {
#pragma unroll
      for (int u = 0; u < 4; ++u)
        atomicMin(&kb[ob * 4 + u], enc(red[u] + wo[u]));
    }
  }
}

// Decode keys, sum all 2*B*N per-point mins, scale by 1/(B*N) (N == M).
__global__ __launch_bounds__(kBlk) void cham_reduce_kernel(
    const unsigned* __restrict__ keys, float* __restrict__ out) {
  __shared__ float red[kBlk];
  float acc = 0.0f;
  for (int i = blockIdx.x * kBlk + threadIdx.x; i < kP; i += gridDim.x * kBlk)
    acc += dec(keys[i]);
  red[threadIdx.x] = acc;
  __syncthreads();
  for (int s = kBlk / 2; s > 0; s >>= 1) {
    if (threadIdx.x < s) red[threadIdx.x] += red[threadIdx.x + s];
    __syncthreads();
  }
  if (threadIdx.x == 0) atomicAdd(out, red[0] * (1.0f / kPts));
}

extern "C" void kernel_launch(void* const* d_in, const int* in_sizes, int n_in,
                              void* d_out, int out_size, void* d_ws,
                              size_t ws_size, hipStream_t stream) {
  const float* src = (const float*)d_in[0];  // (B, N, 3) fp32
  const float* tgt = (const float*)d_in[1];  // (B, M, 3) fp32
  float* out = (float*)d_out;                // scalar fp32

  unsigned* keys = (unsigned*)d_ws;                       // 128 KB
  float* packf = (float*)((char*)d_ws + (size_t)kP * 4);  // 512 KB, 16B-align

  cham_prep_kernel<<<dim3(kP / 2 / kBlk), kBlk, 0, stream>>>(
      src, tgt, (float4*)packf, keys, out);

  // (2 other-segs * 64 own-blocks, B, 2 dirs) = 1024 blocks
  dim3 grid(kOSeg * (kN / kOwnsPerBlk), kB, 2);
  cham_min_kernel<<<grid, kBlk, 0, stream>>>((const float4*)packf, keys);

  cham_reduce_kernel<<<dim3(16), kBlk, 0, stream>>>(keys, out);
}

// Round 3
// 76.432 us; speedup vs baseline: 1.0932x; 1.0932x over previous
//
#include <hip/hip_runtime.h>

typedef float f2 __attribute__((ext_vector_type(2)));

namespace {
constexpr int kB = 4;
constexpr int kN = 4096;             // points per set per batch (N == M)
constexpr int kPts = kB * kN;        // per set = 16384
constexpr int kP = 2 * kPts;         // all per-point mins = 32768
constexpr int kBlk = 256;
constexpr int kOP = 4;               // own points per thread
constexpr int kSplit = 32;           // blocks splitting the inner scan
constexpr int kChunk = kN / kSplit;  // 128 other-points per block
constexpr float kInf = 3.4e38f;
}

// ws layout: [keys: kP u32][pack: kP float4 worth of pair-interleaved floats]
// Pair-interleaved pack: for point pair g, float4 pack4[2g] = {x0,x1,y0,y1},
// pack4[2g+1] = {z0,z1,w0,w1}, w = ||p||^2. Pairs [0, kPts/2) = target set,
// [kPts/2, kP/2) = source set. This layout puts v_pk_fma_f32 operands in
// adjacent registers after the wave-uniform s_load_dwordx4.

// Monotone float<->uint map: unsigned atomicMin orders all floats (partial
// e = ||y||^2 - 2 x.y can be negative).
__device__ __forceinline__ unsigned enc(float f) {
  unsigned u = __float_as_uint(f);
  return (u & 0x80000000u) ? ~u : (u | 0x80000000u);
}
__device__ __forceinline__ float dec(unsigned k) {
  return __uint_as_float((k & 0x80000000u) ? (k ^ 0x80000000u) : ~k);
}

// One thread per point PAIR: contiguous 24B read, two float4 stores, one
// uint2 key-init. Pairs never straddle the set boundary (kPts even).
__global__ __launch_bounds__(kBlk) void cham_prep_kernel(
    const float* __restrict__ src, const float* __restrict__ tgt,
    float4* __restrict__ pack4, unsigned* __restrict__ keys,
    float* __restrict__ out) {
  int g = blockIdx.x * kBlk + threadIdx.x;  // pair id, grid covers kP/2
  const float* p = (g < kPts / 2) ? (tgt + (size_t)g * 6)
                                  : (src + (size_t)(g - kPts / 2) * 6);
  const f2 a = *(const f2*)(p);      // {x0, y0}   (8B-aligned: 24g % 8 == 0)
  const f2 bv = *(const f2*)(p + 2); // {z0, x1}
  const f2 c = *(const f2*)(p + 4);  // {y1, z1}
  const float x0 = a.x, y0 = a.y, z0 = bv.x;
  const float x1 = bv.y, y1 = c.x, z1 = c.y;
  const float w0 = fmaf(x0, x0, fmaf(y0, y0, z0 * z0));
  const float w1 = fmaf(x1, x1, fmaf(y1, y1, z1 * z1));
  pack4[2 * g] = make_float4(x0, x1, y0, y1);
  pack4[2 * g + 1] = make_float4(z0, z1, w0, w1);
  ((uint2*)keys)[g] = make_uint2(0xFFFFFFFFu, 0xFFFFFFFFu);  // +max
  if (g == 0) out[0] = 0.0f;
}

// R1 structure (per-lane owns, wave-uniform s_load others), kOP 2->4:
// one thread = 4 own points read from pack4 (w precomputed), scanning a
// 128-point chunk of the other set. Inner 2-other group:
// 2 wave-uniform s_load_dwordx4 (merged wider across unroll) + 1 shared
// W SGPR->VGPR copy + per own {3 v_pk_fma + 1 v_min3}
//   => 17 VALU / 8 evals = 2.125 instr/eval, and HALF the scalar-fetch
//      bytes + lgkmcnt waits per eval vs kOP=2.
// kSplit 16->32 keeps 4096 waves = 4 waves/SIMD (TLP for s_load latency).
// 8 independent min chains (2 per own, g&1 ping-pong) for ILP.
// NO launch-bounds occupancy pin (R2 post-mortem: forcing 3/SIMD spilled).
__global__ __launch_bounds__(kBlk) void cham_min_kernel(
    const float4* __restrict__ pack4, unsigned* __restrict__ keys) {
  const int dir = blockIdx.z;  // 0: s->t (other = tgt = first half), 1: t->s
  const int b = blockIdx.y;
  const int chunk = blockIdx.x & (kSplit - 1);
  const int ntile = blockIdx.x >> 5;  // kSplit == 32
  const int n0 = (ntile * kBlk + threadIdx.x) * kOP;  // first own point

  // own set: dir==0 -> src (second half of pack), dir==1 -> tgt (first half)
  const size_t ownPair =
      ((size_t)(1 - dir) * kPts + (size_t)b * kN + n0) / 2;
  const float4 A0 = pack4[2 * ownPair + 0];  // {x0,x1,y0,y1}
  const float4 B0 = pack4[2 * ownPair + 1];  // {z0,z1,w0,w1}
  const float4 A1 = pack4[2 * ownPair + 2];  // {x2,x3,y2,y3}
  const float4 B1 = pack4[2 * ownPair + 3];  // {z2,z3,w2,w3}

  const f2 NX[kOP] = {{-2.0f * A0.x, -2.0f * A0.x},
                      {-2.0f * A0.y, -2.0f * A0.y},
                      {-2.0f * A1.x, -2.0f * A1.x},
                      {-2.0f * A1.y, -2.0f * A1.y}};
  const f2 NY[kOP] = {{-2.0f * A0.z, -2.0f * A0.z},
                      {-2.0f * A0.w, -2.0f * A0.w},
                      {-2.0f * A1.z, -2.0f * A1.z},
                      {-2.0f * A1.w, -2.0f * A1.w}};
  const f2 NZ[kOP] = {{-2.0f * B0.x, -2.0f * B0.x},
                      {-2.0f * B0.y, -2.0f * B0.y},
                      {-2.0f * B1.x, -2.0f * B1.x},
                      {-2.0f * B1.y, -2.0f * B1.y}};
  const float wo[kOP] = {B0.z, B0.w, B1.z, B1.w};

  // other-set chunk start, in 2-point groups (2 float4s per group)
  const size_t g0 =
      ((size_t)dir * kPts + (size_t)b * kN + (size_t)chunk * kChunk) / 2;
  const float4* __restrict__ q = pack4 + 2 * g0;

  float ea[kOP], eb[kOP];
#pragma unroll
  for (int k = 0; k < kOP; ++k) { ea[k] = kInf; eb[k] = kInf; }

#pragma unroll 8
  for (int g = 0; g < kChunk / 2; ++g) {  // 64 groups
    const float4 A = q[2 * g + 0];   // {x_a, x_b, y_a, y_b}
    const float4 Bv = q[2 * g + 1];  // {z_a, z_b, w_a, w_b}
    const f2 X = {A.x, A.y}, Y = {A.z, A.w}, Z = {Bv.x, Bv.y};
    const f2 Wv = {Bv.z, Bv.w};  // single SGPR->VGPR copy, shared by 4 owns
#pragma unroll
    for (int k = 0; k < kOP; ++k) {  // static indices -> registers
      const f2 e = __builtin_elementwise_fma(
          NX[k], X,
          __builtin_elementwise_fma(NY[k], Y,
                                    __builtin_elementwise_fma(NZ[k], Z, Wv)));
      if (g & 1) eb[k] = fminf(fminf(e.x, e.y), eb[k]);  // v_min3, 2 chains
      else       ea[k] = fminf(fminf(e.x, e.y), ea[k]);
    }
  }

  unsigned* __restrict__ kb = keys + ((size_t)dir * kB + b) * kN + n0;
#pragma unroll
  for (int k = 0; k < kOP; ++k)
    atomicMin(&kb[k], enc(fminf(ea[k], eb[k]) + wo[k]));
}

// Decode keys, sum all 2*B*N per-point mins, scale by 1/(B*N) (N == M).
__global__ __launch_bounds__(kBlk) void cham_reduce_kernel(
    const unsigned* __restrict__ keys, float* __restrict__ out) {
  __shared__ float red[kBlk];
  float acc = 0.0f;
  for (int i = blockIdx.x * kBlk + threadIdx.x; i < kP; i += gridDim.x * kBlk)
    acc += dec(keys[i]);
  red[threadIdx.x] = acc;
  __syncthreads();
  for (int s = kBlk / 2; s > 0; s >>= 1) {
    if (threadIdx.x < s) red[threadIdx.x] += red[threadIdx.x + s];
    __syncthreads();
  }
  if (threadIdx.x == 0) atomicAdd(out, red[0] * (1.0f / kPts));
}

extern "C" void kernel_launch(void* const* d_in, const int* in_sizes, int n_in,
                              void* d_out, int out_size, void* d_ws,
                              size_t ws_size, hipStream_t stream) {
  const float* src = (const float*)d_in[0];  // (B, N, 3) fp32
  const float* tgt = (const float*)d_in[1];  // (B, M, 3) fp32
  float* out = (float*)d_out;                // scalar fp32

  unsigned* keys = (unsigned*)d_ws;                       // 128 KB
  float* packf = (float*)((char*)d_ws + (size_t)kP * 4);  // 512 KB, 16B-align

  cham_prep_kernel<<<dim3(kP / 2 / kBlk), kBlk, 0, stream>>>(
      src, tgt, (float4*)packf, keys, out);

  // (4 own-tiles * 32 splits, B, 2 dirs) = 1024 blocks, 4096 waves
  dim3 grid(kN / (kBlk * kOP) * kSplit, kB, 2);
  cham_min_kernel<<<grid, kBlk, 0, stream>>>((const float4*)packf, keys);

  cham_reduce_kernel<<<dim3(16), kBlk, 0, stream>>>(keys, out);
}